// Round 1
// baseline (98.587 us; speedup 1.0000x reference)
//
#include <hip/hip_runtime.h>

// Problem: out = ((x@W1.T+b1)@W2.T+b2)@W3.T+b3, with exilu == identity
// (keep-mask is a tautology). Fold into a single [6,6] affine map.
// B = 8388608 rows of 6 fp32. Memory-bound: 402 MB traffic -> ~64 us floor.

// ---- fold kernel: Wc = W3@W2@W1 (6x6), bc = W3@(W2@b1+b2)+b3 (6) ----
__global__ void fold_weights(const float* __restrict__ W1, const float* __restrict__ b1,
                             const float* __restrict__ W2, const float* __restrict__ b2,
                             const float* __restrict__ W3, const float* __restrict__ b3,
                             float* __restrict__ ws) {
    if (threadIdx.x != 0 || blockIdx.x != 0) return;
    // T1 = W2 @ W1 : [8,6]
    float T1[8][6];
    for (int o = 0; o < 8; ++o)
        for (int i = 0; i < 6; ++i) {
            float s = 0.f;
            for (int k = 0; k < 8; ++k) s = fmaf(W2[o * 8 + k], W1[k * 6 + i], s);
            T1[o][i] = s;
        }
    // Wc = W3 @ T1 : [6,6]
    for (int o = 0; o < 6; ++o)
        for (int i = 0; i < 6; ++i) {
            float s = 0.f;
            for (int k = 0; k < 8; ++k) s = fmaf(W3[o * 8 + k], T1[k][i], s);
            ws[o * 6 + i] = s;
        }
    // bb = W2@b1 + b2 : [8]
    float bb[8];
    for (int o = 0; o < 8; ++o) {
        float s = b2[o];
        for (int k = 0; k < 8; ++k) s = fmaf(W2[o * 8 + k], b1[k], s);
        bb[o] = s;
    }
    // bc = W3@bb + b3 : [6]
    for (int o = 0; o < 6; ++o) {
        float s = b3[o];
        for (int k = 0; k < 8; ++k) s = fmaf(W3[o * 8 + k], bb[k], s);
        ws[36 + o] = s;
    }
}

// ---- main kernel: 2 rows/thread, 3x float4 in, 3x float4 out ----
__global__ void __launch_bounds__(256) mlp_folded(const float* __restrict__ x,
                                                  const float* __restrict__ wc,
                                                  float* __restrict__ out,
                                                  int nPairs) {
    // 42 uniform floats -> scalar loads (SGPRs), shared by all lanes.
    float w[36], b[6];
#pragma unroll
    for (int i = 0; i < 36; ++i) w[i] = wc[i];
#pragma unroll
    for (int i = 0; i < 6; ++i) b[i] = wc[36 + i];

    int tid = blockIdx.x * blockDim.x + threadIdx.x;
    int stride = gridDim.x * blockDim.x;
    for (int p = tid; p < nPairs; p += stride) {
        const float4* xp = reinterpret_cast<const float4*>(x + (size_t)p * 12);
        float4 va = xp[0];
        float4 vb = xp[1];
        float4 vc = xp[2];
        float in0[6] = {va.x, va.y, va.z, va.w, vb.x, vb.y};
        float in1[6] = {vb.z, vb.w, vc.x, vc.y, vc.z, vc.w};
        float o0[6], o1[6];
#pragma unroll
        for (int o = 0; o < 6; ++o) {
            float s0 = b[o], s1 = b[o];
#pragma unroll
            for (int i = 0; i < 6; ++i) {
                s0 = fmaf(w[o * 6 + i], in0[i], s0);
                s1 = fmaf(w[o * 6 + i], in1[i], s1);
            }
            o0[o] = s0;
            o1[o] = s1;
        }
        float4 r0 = {o0[0], o0[1], o0[2], o0[3]};
        float4 r1 = {o0[4], o0[5], o1[0], o1[1]};
        float4 r2 = {o1[2], o1[3], o1[4], o1[5]};
        float4* op = reinterpret_cast<float4*>(out + (size_t)p * 12);
        op[0] = r0;
        op[1] = r1;
        op[2] = r2;
    }
}

extern "C" void kernel_launch(void* const* d_in, const int* in_sizes, int n_in,
                              void* d_out, int out_size, void* d_ws, size_t ws_size,
                              hipStream_t stream) {
    const float* x  = (const float*)d_in[0];
    const float* W1 = (const float*)d_in[1];
    const float* b1 = (const float*)d_in[2];
    const float* W2 = (const float*)d_in[3];
    const float* b2 = (const float*)d_in[4];
    const float* W3 = (const float*)d_in[5];
    const float* b3 = (const float*)d_in[6];
    float* out = (float*)d_out;
    float* ws  = (float*)d_ws;

    int B = in_sizes[0] / 6;     // 8388608
    int nPairs = B / 2;          // B is even

    fold_weights<<<1, 64, 0, stream>>>(W1, b1, W2, b2, W3, b3, ws);

    int blocks = (nPairs + 255) / 256;
    if (blocks > 2048) blocks = 2048;
    mlp_folded<<<blocks, 256, 0, stream>>>(x, ws, out, nPairs);
}

// Round 2
// 86.193 us; speedup vs baseline: 1.1438x; 1.1438x over previous
//
#include <hip/hip_runtime.h>

// out = ((x@W1.T+b1)@W2.T+b2)@W3.T+b3 ; exilu == identity (tautological mask)
// => single affine map: out = x @ Wc.T + bc, Wc = W3@W2@W1 [6,6], bc [6].
// B = 8388608 rows x 6 fp32. 402 MB traffic -> ~60 us floor at ~6.5 TB/s.
//
// Access pattern: 6 floats = 2x dwordx3. Lane pair (2j,2j+1) owns row j:
// lane i loads/stores floats [3i, 3i+3) -> 12B lane stride = fully
// contiguous wave accesses. 3x shfl_xor(1) exchanges row halves in-pair.

// ---- fold kernel: Wc = W3@W2@W1 (6x6) -> ws[0..35], bc -> ws[36..41] ----
__global__ void fold_weights(const float* __restrict__ W1, const float* __restrict__ b1,
                             const float* __restrict__ W2, const float* __restrict__ b2,
                             const float* __restrict__ W3, const float* __restrict__ b3,
                             float* __restrict__ ws) {
    if (threadIdx.x != 0 || blockIdx.x != 0) return;
    // T1 = W2 @ W1 : [8,6]
    float T1[8][6];
    for (int o = 0; o < 8; ++o)
        for (int i = 0; i < 6; ++i) {
            float s = 0.f;
            for (int k = 0; k < 8; ++k) s = fmaf(W2[o * 8 + k], W1[k * 6 + i], s);
            T1[o][i] = s;
        }
    // Wc = W3 @ T1 : [6,6]
    for (int o = 0; o < 6; ++o)
        for (int i = 0; i < 6; ++i) {
            float s = 0.f;
            for (int k = 0; k < 8; ++k) s = fmaf(W3[o * 8 + k], T1[k][i], s);
            ws[o * 6 + i] = s;
        }
    // bb = W2@b1 + b2 : [8]
    float bb[8];
    for (int o = 0; o < 8; ++o) {
        float s = b2[o];
        for (int k = 0; k < 8; ++k) s = fmaf(W2[o * 8 + k], b1[k], s);
        bb[o] = s;
    }
    // bc = W3@bb + b3 : [6]
    for (int o = 0; o < 6; ++o) {
        float s = b3[o];
        for (int k = 0; k < 8; ++k) s = fmaf(W3[o * 8 + k], bb[k], s);
        ws[36 + o] = s;
    }
}

struct __align__(4) F3 { float a, b, c; };

// ---- main kernel: unit-stride dwordx3 streaming, pair-cooperative rows ----
__global__ void __launch_bounds__(256) mlp_pair(const float* __restrict__ x,
                                                const float* __restrict__ wc,
                                                float* __restrict__ out,
                                                int nUnits) {
    const int tid    = blockIdx.x * blockDim.x + threadIdx.x;
    const int stride = gridDim.x * blockDim.x;
    const int par    = threadIdx.x & 1;  // 0: row floats 0-2, 1: floats 3-5

    // This lane computes output columns [3*par, 3*par+3) -> needs 3 rows of Wc.
    float w[3][6], bs[3];
#pragma unroll
    for (int r = 0; r < 3; ++r) {
#pragma unroll
        for (int i = 0; i < 6; ++i) w[r][i] = wc[(3 * par + r) * 6 + i];
        bs[r] = wc[36 + 3 * par + r];
    }

    const F3* __restrict__ xv  = reinterpret_cast<const F3*>(x);
    F3* __restrict__       ov  = reinterpret_cast<F3*>(out);

    for (int u = tid; u < nUnits; u += stride) {
        F3 v = xv[u];  // global_load_dwordx3, 12B lane stride (contiguous)

        // partner's 3 floats (lane^1) via quad-perm shuffle
        float pa = __shfl_xor(v.a, 1);
        float pb = __shfl_xor(v.b, 1);
        float pc = __shfl_xor(v.c, 1);

        // reassemble full 6-float row (par selects which half we hold)
        float x0 = par ? pa : v.a;
        float x1 = par ? pb : v.b;
        float x2 = par ? pc : v.c;
        float x3 = par ? v.a : pa;
        float x4 = par ? v.b : pb;
        float x5 = par ? v.c : pc;

        F3 o;
        float* op = &o.a;
#pragma unroll
        for (int r = 0; r < 3; ++r) {
            float s = bs[r];
            s = fmaf(w[r][0], x0, s);
            s = fmaf(w[r][1], x1, s);
            s = fmaf(w[r][2], x2, s);
            s = fmaf(w[r][3], x3, s);
            s = fmaf(w[r][4], x4, s);
            s = fmaf(w[r][5], x5, s);
            op[r] = s;
        }
        ov[u] = o;  // global_store_dwordx3, 12B lane stride (contiguous)
    }
}

extern "C" void kernel_launch(void* const* d_in, const int* in_sizes, int n_in,
                              void* d_out, int out_size, void* d_ws, size_t ws_size,
                              hipStream_t stream) {
    const float* x  = (const float*)d_in[0];
    const float* W1 = (const float*)d_in[1];
    const float* b1 = (const float*)d_in[2];
    const float* W2 = (const float*)d_in[3];
    const float* b2 = (const float*)d_in[4];
    const float* W3 = (const float*)d_in[5];
    const float* b3 = (const float*)d_in[6];
    float* outp = (float*)d_out;
    float* ws   = (float*)d_ws;

    fold_weights<<<1, 64, 0, stream>>>(W1, b1, W2, b2, W3, b3, ws);

    int nUnits = in_sizes[0] / 3;  // 16777216 dwordx3 units (= 2 per row)
    int blocks = 2048;             // 8 blocks/CU, grid-stride 32 units/thread
    mlp_pair<<<blocks, 256, 0, stream>>>(x, ws, outp, nUnits);
}